// Round 4
// baseline (637.447 us; speedup 1.0000x reference)
//
#include <hip/hip_runtime.h>
#include <math.h>

#define NB_CLASSES 1024
#define SZ_EMBED 128
#define N_SAMPLES 262144
#define MTILE 64
#define CTILE 64
#define NBLOCKS (N_SAMPLES / MTILE)  // 4096
#define XSTRIDE 136  // bf16 elems; 272B row stride -> 2-way bank alias only (free per m136)

typedef __bf16 v8bf __attribute__((ext_vector_type(8)));
typedef float v4f __attribute__((ext_vector_type(4)));

// exp(+-32*cos + 3.2) = exp2(46.166...*(+-cos) + 4.6166...)
#define EXP_A 46.16624130844683f
#define EXP_B 4.616624130844683f

// R12: occupancy attack via 2-pass row-group split.
//  - R11 post-mortem: nt X loads HURT (FETCH 67->97MB: the 67 was X served
//    from L3, which fits 134MB across bench iters) -> reverted. WRITE's
//    extra 16MB over logical is the pos_g/negd_g device atomics, not store
//    amplification -> ignore. Occupancy pinned at 41% (3 waves/SIMD) by
//    afrag[4][4]+acc AGPR footprint (~140 total regs).
//  - This round: afrag[2][4] (32) + acc x2 (8) + bfrag[4] (16) ~= 95 total
//    -> 4-5 waves/SIMD. Two passes over row groups; per-pass results go to
//    cls[rg][] in LDS (disjoint per wave, no sync needed until copy-out).
//    This is R9's split WITHOUT the spill sources (no e_acc[16], no double
//    bfrag). Pn L2 traffic x2 is cheap (34.5 TB/s aggregate).
#define SMEM_BYTES 27904

__device__ __forceinline__ unsigned short f2bf(float f) {
    union { float f; unsigned u; } v; v.f = f;
    unsigned u = v.u;
    unsigned rounding = 0x7FFFu + ((u >> 16) & 1u);
    return (unsigned short)((u + rounding) >> 16);
}
__device__ __forceinline__ float bfbits_lo(unsigned u) {
    union { unsigned u; float f; } v; v.u = u << 16; return v.f;
}
__device__ __forceinline__ float bfbits_hi(unsigned u) {
    union { unsigned u; float f; } v; v.u = u & 0xffff0000u; return v.f;
}

__global__ __launch_bounds__(256) void norm_proxies_kernel(
    const float* __restrict__ proxies, unsigned short* __restrict__ pn) {
    int wv = threadIdx.x >> 6;
    int lane = threadIdx.x & 63;
    int row = blockIdx.x * 4 + wv;  // grid = 256 -> rows 0..1023
    const float* src = proxies + (size_t)row * SZ_EMBED + lane * 2;
    float2 x = *(const float2*)src;
    float ss = x.x * x.x + x.y * x.y;
    #pragma unroll
    for (int off = 32; off; off >>= 1) ss += __shfl_xor(ss, off);
    float inv = rsqrtf(ss + 1e-12f);
    unsigned pk = (unsigned)f2bf(x.x * inv) | ((unsigned)f2bf(x.y * inv) << 16);
    *(unsigned*)(pn + (size_t)row * SZ_EMBED + lane * 2) = pk;
}

__global__ __launch_bounds__(256, 4) void main_kernel(
    const float* __restrict__ X, const int* __restrict__ T,
    const unsigned short* __restrict__ Pn,
    float* __restrict__ partial_neg, float* __restrict__ pos_g,
    float* __restrict__ negd_g) {
    __shared__ __align__(16) char smem[SMEM_BYTES];
    unsigned short* xtile = (unsigned short*)smem;          // 64 x 136 bf16 = 17408 B
    float (*psum)[4] = (float(*)[4])(smem + 17408);
    float (*dsum)[4] = (float(*)[4])(smem + 18432);
    int* tT = (int*)(smem + 19456);
    float* cls = (float*)(smem + 19712);                    // [2][1024] floats, 8 KB

    const int t = threadIdx.x;
    const int lane = t & 63;
    const int wv = t >> 6;
    const int quad = lane >> 4;
    const int l15 = lane & 15;
    const int sample_base = blockIdx.x * MTILE;
    const int row = t >> 2, part = t & 3;  // 4 threads per sample row, 32 cols each

    // ---- phase A: load + normalize X tile into bf16 LDS; diag dot -> global atomics ----
    {
        const float4* src = (const float4*)(X + (size_t)(sample_base + row) * SZ_EMBED + part * 32);
        float4 r[8];
        float ss = 0.f;
        #pragma unroll
        for (int j = 0; j < 8; ++j) {
            r[j] = src[j];
            ss += r[j].x * r[j].x + r[j].y * r[j].y + r[j].z * r[j].z + r[j].w * r[j].w;
        }
        psum[row][part] = ss;
        if (t < MTILE) tT[t] = T[sample_base + t];
        __syncthreads();
        float inv = rsqrtf(psum[row][0] + psum[row][1] + psum[row][2] + psum[row][3] + 1e-12f);
        unsigned short* dst = xtile + row * XSTRIDE + part * 32;
        #pragma unroll
        for (int j = 0; j < 8; ++j) {
            uint2 pk;
            pk.x = (unsigned)f2bf(r[j].x * inv) | ((unsigned)f2bf(r[j].y * inv) << 16);
            pk.y = (unsigned)f2bf(r[j].z * inv) | ((unsigned)f2bf(r[j].w * inv) << 16);
            *(uint2*)(dst + j * 4) = pk;
        }
        // diag partial: dot(X[row]*inv, Pn[T[row]]) over this thread's 32 cols
        int lbl = tT[row];
        const unsigned short* prow = Pn + (size_t)lbl * SZ_EMBED + part * 32;
        float d = 0.f;
        #pragma unroll
        for (int j = 0; j < 4; ++j) {  // 4 x uint4 = 32 cols
            uint4 pv = *(const uint4*)(prow + j * 8);
            float4 xa = r[2 * j], xb = r[2 * j + 1];
            d += bfbits_lo(pv.x) * xa.x + bfbits_hi(pv.x) * xa.y;
            d += bfbits_lo(pv.y) * xa.z + bfbits_hi(pv.y) * xa.w;
            d += bfbits_lo(pv.z) * xb.x + bfbits_hi(pv.z) * xb.y;
            d += bfbits_lo(pv.w) * xb.z + bfbits_hi(pv.w) * xb.w;
        }
        dsum[row][part] = d * inv;
        __syncthreads();  // xtile + dsum ready; xtile never clobbered after this
        if (part == 0) {
            int lbl2 = tT[row];
            float dd = dsum[row][0] + dsum[row][1] + dsum[row][2] + dsum[row][3];
            float dp = __builtin_amdgcn_exp2f(fmaf(dd, -EXP_A, EXP_B));  // exp(-a(cos-mrg))
            float dn = __builtin_amdgcn_exp2f(fmaf(dd,  EXP_A, EXP_B));  // exp(+a(cos+mrg))
            atomicAdd(&pos_g[lbl2], dp);   // only contribution to pos sums
            atomicAdd(&negd_g[lbl2], dn);  // subtracted from neg sums in finalize
        }
    }

    // ---- class loop, 2 row-group passes. Wave wv owns col strip wv*16+l15 of
    // each 64-class tile. Per pass: afrag[2][4] resident (32 regs), single
    // bfrag[4]; MFMAs consume, prefetch next tile, epilogue hides L2 latency.
    const unsigned short* bptr = Pn + (size_t)(wv * 16 + l15) * SZ_EMBED + quad * 8;

    #pragma unroll 1
    for (int rg = 0; rg < 2; ++rg) {
        v8bf afrag[2][4];
        #pragma unroll
        for (int ri = 0; ri < 2; ++ri)
            #pragma unroll
            for (int kc = 0; kc < 4; ++kc)
                afrag[ri][kc] = *(const v8bf*)(xtile + (rg * 32 + ri * 16 + l15) * XSTRIDE + kc * 32 + quad * 8);

        v8bf bfrag[4];
        #pragma unroll
        for (int kc = 0; kc < 4; ++kc)
            bfrag[kc] = *(const v8bf*)(bptr + kc * 32);

        float* clsrg = cls + rg * NB_CLASSES + wv * 16 + l15;

        #pragma unroll
        for (int ct = 0; ct < NB_CLASSES / CTILE; ++ct) {
            v4f zero = {0.f, 0.f, 0.f, 0.f};
            v4f acc0 = zero, acc1 = zero;
            #pragma unroll
            for (int kc = 0; kc < 4; ++kc) {
                acc0 = __builtin_amdgcn_mfma_f32_16x16x32_bf16(afrag[0][kc], bfrag[kc], acc0, 0, 0, 0);
                acc1 = __builtin_amdgcn_mfma_f32_16x16x32_bf16(afrag[1][kc], bfrag[kc], acc1, 0, 0, 0);
            }
            // issue next tile's loads (bfrag fully consumed); epilogue hides latency
            if (ct < NB_CLASSES / CTILE - 1) {
                const unsigned short* nb = bptr + (size_t)(ct + 1) * CTILE * SZ_EMBED;
                #pragma unroll
                for (int kc = 0; kc < 4; ++kc)
                    bfrag[kc] = *(const v8bf*)(nb + kc * 32);
            }
            // epilogue: 8 exp2 + tree + cross-quad butterfly; quad-0 lanes park
            // result in LDS (bank-clean: 16 lanes hit banks wv*16+{0..15}).
            float e0 = __builtin_amdgcn_exp2f(fmaf(acc0[0], EXP_A, EXP_B));
            float e1 = __builtin_amdgcn_exp2f(fmaf(acc0[1], EXP_A, EXP_B));
            float e2 = __builtin_amdgcn_exp2f(fmaf(acc0[2], EXP_A, EXP_B));
            float e3 = __builtin_amdgcn_exp2f(fmaf(acc0[3], EXP_A, EXP_B));
            float e4 = __builtin_amdgcn_exp2f(fmaf(acc1[0], EXP_A, EXP_B));
            float e5 = __builtin_amdgcn_exp2f(fmaf(acc1[1], EXP_A, EXP_B));
            float e6 = __builtin_amdgcn_exp2f(fmaf(acc1[2], EXP_A, EXP_B));
            float e7 = __builtin_amdgcn_exp2f(fmaf(acc1[3], EXP_A, EXP_B));
            float vsum = ((e0 + e1) + (e2 + e3)) + ((e4 + e5) + (e6 + e7));
            vsum += __shfl_xor(vsum, 16);
            vsum += __shfl_xor(vsum, 32);
            if (quad == 0) clsrg[ct * CTILE] = vsum;
        }
    }

    // ---- coalesced copy-out: sum the two pass arrays, 256 threads x float4 ----
    __syncthreads();
    float* nrow = partial_neg + (size_t)blockIdx.x * NB_CLASSES;
    v4f v0 = *(const v4f*)(cls + 4 * t);
    v4f v1 = *(const v4f*)(cls + NB_CLASSES + 4 * t);
    *(v4f*)(nrow + 4 * t) = v0 + v1;
}

// 256 blocks, neg only. Block (g,q): sums rows [g*64, g*64+64) of class
// columns [q*256, q*256+256) into row g*64. 256 threads = 1 KB contiguous/row.
__global__ __launch_bounds__(256) void row_reduce_kernel(float* __restrict__ partial_neg) {
    const int t = threadIdx.x;
    const int g = blockIdx.x >> 2, q = blockIdx.x & 3;
    float* base = partial_neg + (size_t)g * 64 * NB_CLASSES + q * 256 + t;
    float s = 0.f;
    #pragma unroll 8
    for (int r = 0; r < 64; ++r) s += base[(size_t)r * NB_CLASSES];
    base[0] = s;
}

__global__ __launch_bounds__(256) void finalize_kernel(
    const float* __restrict__ partial_neg, const float* __restrict__ pos_g,
    const float* __restrict__ negd_g, float* __restrict__ out) {
    int t = threadIdx.x;
    // surviving neg rows: {0, 64, 128, ..., 4032}
    float4 ns = {0.f, 0.f, 0.f, 0.f};
    #pragma unroll 8
    for (int r = 0; r < 64; ++r) {
        float4 vn = *(const float4*)(partial_neg + (size_t)r * 64 * NB_CLASSES + 4 * t);
        ns.x += vn.x; ns.y += vn.y; ns.z += vn.z; ns.w += vn.w;
    }
    float4 nd = *(const float4*)(negd_g + 4 * t);
    ns.x -= nd.x; ns.y -= nd.y; ns.z -= nd.z; ns.w -= nd.w;
    float4 ps = *(const float4*)(pos_g + 4 * t);
    float lp_pos = log1pf(ps.x) + log1pf(ps.y) + log1pf(ps.z) + log1pf(ps.w);
    float lp_neg = log1pf(ns.x) + log1pf(ns.y) + log1pf(ns.z) + log1pf(ns.w);
    float valid = (ps.x != 0.f) + (ps.y != 0.f) + (ps.z != 0.f) + (ps.w != 0.f);
    #pragma unroll
    for (int off = 32; off; off >>= 1) {
        lp_pos += __shfl_xor(lp_pos, off);
        lp_neg += __shfl_xor(lp_neg, off);
        valid  += __shfl_xor(valid, off);
    }
    __shared__ float s[3][4];
    int wv = t >> 6, lane = t & 63;
    if (lane == 0) { s[0][wv] = lp_pos; s[1][wv] = lp_neg; s[2][wv] = valid; }
    __syncthreads();
    if (t == 0) {
        float P = s[0][0] + s[0][1] + s[0][2] + s[0][3];
        float Ng = s[1][0] + s[1][1] + s[1][2] + s[1][3];
        float V = s[2][0] + s[2][1] + s[2][2] + s[2][3];
        float pos_term = (V > 0.f) ? (P / fmaxf(V, 1.f)) : 0.f;
        float neg_term = Ng / (float)NB_CLASSES;
        out[0] = pos_term + neg_term;
        out[1] = pos_term;
        out[2] = neg_term;
    }
}

extern "C" void kernel_launch(void* const* d_in, const int* in_sizes, int n_in,
                              void* d_out, int out_size, void* d_ws, size_t ws_size,
                              hipStream_t stream) {
    const float* X = (const float*)d_in[0];
    const float* proxies = (const float*)d_in[1];
    const int* T = (const int*)d_in[2];
    float* out = (float*)d_out;

    // ws layout: Pn (256 KB) | pos_g (4 KB) | negd_g (4 KB) | partial_neg (16 MB)
    char* ws = (char*)d_ws;
    unsigned short* Pn = (unsigned short*)ws;
    float* pos_g = (float*)(ws + (size_t)NB_CLASSES * SZ_EMBED * sizeof(unsigned short));
    float* negd_g = pos_g + NB_CLASSES;
    float* partial_neg = negd_g + NB_CLASSES;

    hipMemsetAsync(pos_g, 0, 2 * NB_CLASSES * sizeof(float), stream);
    norm_proxies_kernel<<<NB_CLASSES / 4, 256, 0, stream>>>(proxies, Pn);
    main_kernel<<<NBLOCKS, 256, 0, stream>>>(X, T, Pn, partial_neg, pos_g, negd_g);
    row_reduce_kernel<<<256, 256, 0, stream>>>(partial_neg);
    finalize_kernel<<<1, 256, 0, stream>>>(partial_neg, pos_g, negd_g, out);
}

// Round 5
// 425.031 us; speedup vs baseline: 1.4998x; 1.4998x over previous
//
#include <hip/hip_runtime.h>
#include <math.h>

#define NB_CLASSES 1024
#define SZ_EMBED 128
#define N_SAMPLES 262144
#define MTILE 64
#define CTILE 64
#define NBLOCKS (N_SAMPLES / MTILE)  // 4096
#define XSTRIDE 136  // bf16 elems; 272B row stride -> 2-way bank alias only (free per m136)

typedef __bf16 v8bf __attribute__((ext_vector_type(8)));
typedef float v4f __attribute__((ext_vector_type(4)));

// exp(+-32*cos + 3.2) = exp2(46.166...*(+-cos) + 4.6166...)
#define EXP_A 46.16624130844683f
#define EXP_B 4.616624130844683f

// R13: occupancy via re-tiling, NOT via outer loop.
//  - R12 post-mortem: spill signature (FETCH 853MB/WRITE 822MB) despite
//    LOWER class-loop reg demand than clean R10 (56 vs 96 matrix regs).
//    Common factor of both spill disasters (R9, R12): a rolled rg outer
//    loop around the unrolled class loop -> compiler keeps both row-groups'
//    state live (loop-carried phis) and regalloc explodes. RULE: no rolled
//    outer loop around the class loop.
//  - This round: single-pass 2x2 wave grid. Each wave owns 32 samples x
//    32 classes: afrag[2][4]=32 resident + bfrag[2][4]=32 + acc[2][2]=16
//    = 80 matrix regs (R10: 96). Total ~124 vs R10's ~140 -> crosses the
//    128 boundary -> 4 waves/SIMD (Occupancy 41->50%). Schedule shape
//    identical to proven R10: full unroll, prefetch-after-MFMA, single
//    bfrag buffer. Cross-wr merge via disjoint cls[2][1024] LDS slots.
//  - B-tile reads double (2 waves/class row) but second wave hits L1.
#define SMEM_BYTES 27904

__device__ __forceinline__ unsigned short f2bf(float f) {
    union { float f; unsigned u; } v; v.f = f;
    unsigned u = v.u;
    unsigned rounding = 0x7FFFu + ((u >> 16) & 1u);
    return (unsigned short)((u + rounding) >> 16);
}
__device__ __forceinline__ float bfbits_lo(unsigned u) {
    union { unsigned u; float f; } v; v.u = u << 16; return v.f;
}
__device__ __forceinline__ float bfbits_hi(unsigned u) {
    union { unsigned u; float f; } v; v.u = u & 0xffff0000u; return v.f;
}

__global__ __launch_bounds__(256) void norm_proxies_kernel(
    const float* __restrict__ proxies, unsigned short* __restrict__ pn) {
    int wv = threadIdx.x >> 6;
    int lane = threadIdx.x & 63;
    int row = blockIdx.x * 4 + wv;  // grid = 256 -> rows 0..1023
    const float* src = proxies + (size_t)row * SZ_EMBED + lane * 2;
    float2 x = *(const float2*)src;
    float ss = x.x * x.x + x.y * x.y;
    #pragma unroll
    for (int off = 32; off; off >>= 1) ss += __shfl_xor(ss, off);
    float inv = rsqrtf(ss + 1e-12f);
    unsigned pk = (unsigned)f2bf(x.x * inv) | ((unsigned)f2bf(x.y * inv) << 16);
    *(unsigned*)(pn + (size_t)row * SZ_EMBED + lane * 2) = pk;
}

__global__ __launch_bounds__(256, 4) void main_kernel(
    const float* __restrict__ X, const int* __restrict__ T,
    const unsigned short* __restrict__ Pn,
    float* __restrict__ partial_neg, float* __restrict__ pos_g,
    float* __restrict__ negd_g) {
    __shared__ __align__(16) char smem[SMEM_BYTES];
    unsigned short* xtile = (unsigned short*)smem;          // 64 x 136 bf16 = 17408 B
    float (*psum)[4] = (float(*)[4])(smem + 17408);
    float (*dsum)[4] = (float(*)[4])(smem + 18432);
    int* tT = (int*)(smem + 19456);
    float* cls = (float*)(smem + 19712);                    // [2][1024] floats, 8 KB

    const int t = threadIdx.x;
    const int lane = t & 63;
    const int wv = t >> 6;
    const int quad = lane >> 4;
    const int l15 = lane & 15;
    const int wr = wv >> 1;   // sample half: rows wr*32..wr*32+31
    const int wc = wv & 1;    // class half: cols wc*32..wc*32+31 of each ct tile
    const int sample_base = blockIdx.x * MTILE;
    const int row = t >> 2, part = t & 3;  // 4 threads per sample row, 32 cols each

    // ---- phase A: load + normalize X tile into bf16 LDS; diag dot -> global atomics ----
    {
        const float4* src = (const float4*)(X + (size_t)(sample_base + row) * SZ_EMBED + part * 32);
        float4 r[8];
        float ss = 0.f;
        #pragma unroll
        for (int j = 0; j < 8; ++j) {
            r[j] = src[j];
            ss += r[j].x * r[j].x + r[j].y * r[j].y + r[j].z * r[j].z + r[j].w * r[j].w;
        }
        psum[row][part] = ss;
        if (t < MTILE) tT[t] = T[sample_base + t];
        __syncthreads();
        float inv = rsqrtf(psum[row][0] + psum[row][1] + psum[row][2] + psum[row][3] + 1e-12f);
        unsigned short* dst = xtile + row * XSTRIDE + part * 32;
        #pragma unroll
        for (int j = 0; j < 8; ++j) {
            uint2 pk;
            pk.x = (unsigned)f2bf(r[j].x * inv) | ((unsigned)f2bf(r[j].y * inv) << 16);
            pk.y = (unsigned)f2bf(r[j].z * inv) | ((unsigned)f2bf(r[j].w * inv) << 16);
            *(uint2*)(dst + j * 4) = pk;
        }
        // diag partial: dot(X[row]*inv, Pn[T[row]]) over this thread's 32 cols
        int lbl = tT[row];
        const unsigned short* prow = Pn + (size_t)lbl * SZ_EMBED + part * 32;
        float d = 0.f;
        #pragma unroll
        for (int j = 0; j < 4; ++j) {  // 4 x uint4 = 32 cols
            uint4 pv = *(const uint4*)(prow + j * 8);
            float4 xa = r[2 * j], xb = r[2 * j + 1];
            d += bfbits_lo(pv.x) * xa.x + bfbits_hi(pv.x) * xa.y;
            d += bfbits_lo(pv.y) * xa.z + bfbits_hi(pv.y) * xa.w;
            d += bfbits_lo(pv.z) * xb.x + bfbits_hi(pv.z) * xb.y;
            d += bfbits_lo(pv.w) * xb.z + bfbits_hi(pv.w) * xb.w;
        }
        dsum[row][part] = d * inv;
        __syncthreads();  // xtile + dsum ready; xtile never clobbered after this
        if (part == 0) {
            int lbl2 = tT[row];
            float dd = dsum[row][0] + dsum[row][1] + dsum[row][2] + dsum[row][3];
            float dp = __builtin_amdgcn_exp2f(fmaf(dd, -EXP_A, EXP_B));  // exp(-a(cos-mrg))
            float dn = __builtin_amdgcn_exp2f(fmaf(dd,  EXP_A, EXP_B));  // exp(+a(cos+mrg))
            atomicAdd(&pos_g[lbl2], dp);   // only contribution to pos sums
            atomicAdd(&negd_g[lbl2], dn);  // subtracted from neg sums in finalize
        }
    }

    // ---- extract A fragments: this wave's 32 sample rows (wr half) ----
    v8bf afrag[2][4];
    #pragma unroll
    for (int ri = 0; ri < 2; ++ri)
        #pragma unroll
        for (int kc = 0; kc < 4; ++kc)
            afrag[ri][kc] = *(const v8bf*)(xtile + (wr * 32 + ri * 16 + l15) * XSTRIDE + kc * 32 + quad * 8);

    // ---- class loop: barrier-free, single-pass, full unroll (R10 schedule).
    // Wave (wr,wc) computes 32 samples x 32 classes per ct tile via 16 MFMAs.
    const unsigned short* bptr = Pn + (size_t)(wc * 32 + l15) * SZ_EMBED + quad * 8;
    v8bf bfrag[2][4];
    #pragma unroll
    for (int ci = 0; ci < 2; ++ci)
        #pragma unroll
        for (int kc = 0; kc < 4; ++kc)
            bfrag[ci][kc] = *(const v8bf*)(bptr + ci * 16 * SZ_EMBED + kc * 32);

    float* clsw = cls + wr * NB_CLASSES + wc * 32 + l15;

    #pragma unroll
    for (int ct = 0; ct < NB_CLASSES / CTILE; ++ct) {
        v4f zero = {0.f, 0.f, 0.f, 0.f};
        v4f acc00 = zero, acc01 = zero, acc10 = zero, acc11 = zero;
        #pragma unroll
        for (int kc = 0; kc < 4; ++kc) {
            acc00 = __builtin_amdgcn_mfma_f32_16x16x32_bf16(afrag[0][kc], bfrag[0][kc], acc00, 0, 0, 0);
            acc01 = __builtin_amdgcn_mfma_f32_16x16x32_bf16(afrag[0][kc], bfrag[1][kc], acc01, 0, 0, 0);
            acc10 = __builtin_amdgcn_mfma_f32_16x16x32_bf16(afrag[1][kc], bfrag[0][kc], acc10, 0, 0, 0);
            acc11 = __builtin_amdgcn_mfma_f32_16x16x32_bf16(afrag[1][kc], bfrag[1][kc], acc11, 0, 0, 0);
        }
        // issue next tile's loads (bfrag fully consumed above); epilogue hides latency
        if (ct < NB_CLASSES / CTILE - 1) {
            const unsigned short* nb = bptr + (size_t)(ct + 1) * CTILE * SZ_EMBED;
            #pragma unroll
            for (int ci = 0; ci < 2; ++ci)
                #pragma unroll
                for (int kc = 0; kc < 4; ++kc)
                    bfrag[ci][kc] = *(const v8bf*)(nb + ci * 16 * SZ_EMBED + kc * 32);
        }
        // epilogue: per class strip ci, sum exp2 over this wave's 32 rows:
        // 8 in-lane values (acc[0][ci] + acc[1][ci]) then cross-quad butterfly.
        // quad-0 lanes write LDS (banks ci*16+{0..15} + wc*32: conflict-free).
        {
            float e0 = __builtin_amdgcn_exp2f(fmaf(acc00[0], EXP_A, EXP_B));
            float e1 = __builtin_amdgcn_exp2f(fmaf(acc00[1], EXP_A, EXP_B));
            float e2 = __builtin_amdgcn_exp2f(fmaf(acc00[2], EXP_A, EXP_B));
            float e3 = __builtin_amdgcn_exp2f(fmaf(acc00[3], EXP_A, EXP_B));
            float e4 = __builtin_amdgcn_exp2f(fmaf(acc10[0], EXP_A, EXP_B));
            float e5 = __builtin_amdgcn_exp2f(fmaf(acc10[1], EXP_A, EXP_B));
            float e6 = __builtin_amdgcn_exp2f(fmaf(acc10[2], EXP_A, EXP_B));
            float e7 = __builtin_amdgcn_exp2f(fmaf(acc10[3], EXP_A, EXP_B));
            float v = ((e0 + e1) + (e2 + e3)) + ((e4 + e5) + (e6 + e7));
            v += __shfl_xor(v, 16);
            v += __shfl_xor(v, 32);
            if (quad == 0) clsw[ct * CTILE] = v;
        }
        {
            float e0 = __builtin_amdgcn_exp2f(fmaf(acc01[0], EXP_A, EXP_B));
            float e1 = __builtin_amdgcn_exp2f(fmaf(acc01[1], EXP_A, EXP_B));
            float e2 = __builtin_amdgcn_exp2f(fmaf(acc01[2], EXP_A, EXP_B));
            float e3 = __builtin_amdgcn_exp2f(fmaf(acc01[3], EXP_A, EXP_B));
            float e4 = __builtin_amdgcn_exp2f(fmaf(acc11[0], EXP_A, EXP_B));
            float e5 = __builtin_amdgcn_exp2f(fmaf(acc11[1], EXP_A, EXP_B));
            float e6 = __builtin_amdgcn_exp2f(fmaf(acc11[2], EXP_A, EXP_B));
            float e7 = __builtin_amdgcn_exp2f(fmaf(acc11[3], EXP_A, EXP_B));
            float v = ((e0 + e1) + (e2 + e3)) + ((e4 + e5) + (e6 + e7));
            v += __shfl_xor(v, 16);
            v += __shfl_xor(v, 32);
            if (quad == 0) clsw[ct * CTILE + 16] = v;
        }
    }

    // ---- coalesced copy-out: sum the two wr halves, 256 threads x float4 ----
    __syncthreads();
    float* nrow = partial_neg + (size_t)blockIdx.x * NB_CLASSES;
    v4f v0 = *(const v4f*)(cls + 4 * t);
    v4f v1 = *(const v4f*)(cls + NB_CLASSES + 4 * t);
    *(v4f*)(nrow + 4 * t) = v0 + v1;
}

// 256 blocks, neg only. Block (g,q): sums rows [g*64, g*64+64) of class
// columns [q*256, q*256+256) into row g*64. 256 threads = 1 KB contiguous/row.
__global__ __launch_bounds__(256) void row_reduce_kernel(float* __restrict__ partial_neg) {
    const int t = threadIdx.x;
    const int g = blockIdx.x >> 2, q = blockIdx.x & 3;
    float* base = partial_neg + (size_t)g * 64 * NB_CLASSES + q * 256 + t;
    float s = 0.f;
    #pragma unroll 8
    for (int r = 0; r < 64; ++r) s += base[(size_t)r * NB_CLASSES];
    base[0] = s;
}

__global__ __launch_bounds__(256) void finalize_kernel(
    const float* __restrict__ partial_neg, const float* __restrict__ pos_g,
    const float* __restrict__ negd_g, float* __restrict__ out) {
    int t = threadIdx.x;
    // surviving neg rows: {0, 64, 128, ..., 4032}
    float4 ns = {0.f, 0.f, 0.f, 0.f};
    #pragma unroll 8
    for (int r = 0; r < 64; ++r) {
        float4 vn = *(const float4*)(partial_neg + (size_t)r * 64 * NB_CLASSES + 4 * t);
        ns.x += vn.x; ns.y += vn.y; ns.z += vn.z; ns.w += vn.w;
    }
    float4 nd = *(const float4*)(negd_g + 4 * t);
    ns.x -= nd.x; ns.y -= nd.y; ns.z -= nd.z; ns.w -= nd.w;
    float4 ps = *(const float4*)(pos_g + 4 * t);
    float lp_pos = log1pf(ps.x) + log1pf(ps.y) + log1pf(ps.z) + log1pf(ps.w);
    float lp_neg = log1pf(ns.x) + log1pf(ns.y) + log1pf(ns.z) + log1pf(ns.w);
    float valid = (ps.x != 0.f) + (ps.y != 0.f) + (ps.z != 0.f) + (ps.w != 0.f);
    #pragma unroll
    for (int off = 32; off; off >>= 1) {
        lp_pos += __shfl_xor(lp_pos, off);
        lp_neg += __shfl_xor(lp_neg, off);
        valid  += __shfl_xor(valid, off);
    }
    __shared__ float s[3][4];
    int wv = t >> 6, lane = t & 63;
    if (lane == 0) { s[0][wv] = lp_pos; s[1][wv] = lp_neg; s[2][wv] = valid; }
    __syncthreads();
    if (t == 0) {
        float P = s[0][0] + s[0][1] + s[0][2] + s[0][3];
        float Ng = s[1][0] + s[1][1] + s[1][2] + s[1][3];
        float V = s[2][0] + s[2][1] + s[2][2] + s[2][3];
        float pos_term = (V > 0.f) ? (P / fmaxf(V, 1.f)) : 0.f;
        float neg_term = Ng / (float)NB_CLASSES;
        out[0] = pos_term + neg_term;
        out[1] = pos_term;
        out[2] = neg_term;
    }
}

extern "C" void kernel_launch(void* const* d_in, const int* in_sizes, int n_in,
                              void* d_out, int out_size, void* d_ws, size_t ws_size,
                              hipStream_t stream) {
    const float* X = (const float*)d_in[0];
    const float* proxies = (const float*)d_in[1];
    const int* T = (const int*)d_in[2];
    float* out = (float*)d_out;

    // ws layout: Pn (256 KB) | pos_g (4 KB) | negd_g (4 KB) | partial_neg (16 MB)
    char* ws = (char*)d_ws;
    unsigned short* Pn = (unsigned short*)ws;
    float* pos_g = (float*)(ws + (size_t)NB_CLASSES * SZ_EMBED * sizeof(unsigned short));
    float* negd_g = pos_g + NB_CLASSES;
    float* partial_neg = negd_g + NB_CLASSES;

    hipMemsetAsync(pos_g, 0, 2 * NB_CLASSES * sizeof(float), stream);
    norm_proxies_kernel<<<NB_CLASSES / 4, 256, 0, stream>>>(proxies, Pn);
    main_kernel<<<NBLOCKS, 256, 0, stream>>>(X, T, Pn, partial_neg, pos_g, negd_g);
    row_reduce_kernel<<<256, 256, 0, stream>>>(partial_neg);
    finalize_kernel<<<1, 256, 0, stream>>>(partial_neg, pos_g, negd_g, out);
}

// Round 6
// 342.738 us; speedup vs baseline: 1.8599x; 1.2401x over previous
//
#include <hip/hip_runtime.h>
#include <math.h>

#define NB_CLASSES 1024
#define SZ_EMBED 128
#define N_SAMPLES 262144
#define MTILE 64
#define CTILE 64
#define NBLOCKS (N_SAMPLES / MTILE)  // 4096
#define XSTRIDE 136  // bf16 elems; 272B row stride -> 2-way bank alias only (free per m136)

typedef __bf16 v8bf __attribute__((ext_vector_type(8)));
typedef float v4f __attribute__((ext_vector_type(4)));

// exp(+-32*cos + 3.2) = exp2(46.166...*(+-cos) + 4.6166...)
#define EXP_A 46.16624130844683f
#define EXP_B 4.616624130844683f

// R14: double-buffered B prefetch on the proven R10 structure.
//  - R13 post-mortem: occupancy 42->53% made it 100us SLOWER. Doubled
//    per-wave B-loads (8 vs 4/iter) -> 32KB/CU/iter B footprint = L1
//    thrash across 3-4 unsynchronized resident blocks. Occupancy is NOT
//    the lever; per-wave load count/footprint and per-iter latency
//    exposure are.
//  - All clean ~175us kernels share one defect: single bfrag, prefetch
//    issued AFTER MFMAs -> only the ~200cyc epilogue covers a 200-400cyc
//    L2 round trip = exposed stall every iter, lockstep across waves.
//  - Fix: bfrag[2][4], prefetch ct+1 at TOP of iter (issue->consume = one
//    full iter ~350+cyc). +16 regs (~112 matrix total); flat
//    __launch_bounds__(256) (NO ,4 cap: both spill disasters R9/R12 were
//    under the forced 128-reg cap; ~170 regs stays in R8's 3-waves/SIMD
//    bracket). Class loop fully unrolled, no rolled outer loop (R12 rule).
//  - Spill tripwire: FETCH/WRITE ballooning past ~100MB = falsified.
#define SMEM_BYTES 19712

__device__ __forceinline__ unsigned short f2bf(float f) {
    union { float f; unsigned u; } v; v.f = f;
    unsigned u = v.u;
    unsigned rounding = 0x7FFFu + ((u >> 16) & 1u);
    return (unsigned short)((u + rounding) >> 16);
}
__device__ __forceinline__ float bfbits_lo(unsigned u) {
    union { unsigned u; float f; } v; v.u = u << 16; return v.f;
}
__device__ __forceinline__ float bfbits_hi(unsigned u) {
    union { unsigned u; float f; } v; v.u = u & 0xffff0000u; return v.f;
}

__global__ __launch_bounds__(256) void norm_proxies_kernel(
    const float* __restrict__ proxies, unsigned short* __restrict__ pn) {
    int wv = threadIdx.x >> 6;
    int lane = threadIdx.x & 63;
    int row = blockIdx.x * 4 + wv;  // grid = 256 -> rows 0..1023
    const float* src = proxies + (size_t)row * SZ_EMBED + lane * 2;
    float2 x = *(const float2*)src;
    float ss = x.x * x.x + x.y * x.y;
    #pragma unroll
    for (int off = 32; off; off >>= 1) ss += __shfl_xor(ss, off);
    float inv = rsqrtf(ss + 1e-12f);
    unsigned pk = (unsigned)f2bf(x.x * inv) | ((unsigned)f2bf(x.y * inv) << 16);
    *(unsigned*)(pn + (size_t)row * SZ_EMBED + lane * 2) = pk;
}

__global__ __launch_bounds__(256) void main_kernel(
    const float* __restrict__ X, const int* __restrict__ T,
    const unsigned short* __restrict__ Pn,
    float* __restrict__ partial_neg, float* __restrict__ pos_g,
    float* __restrict__ negd_g) {
    __shared__ __align__(16) char smem[SMEM_BYTES];
    unsigned short* xtile = (unsigned short*)smem;          // 64 x 136 bf16 = 17408 B
    float (*psum)[4] = (float(*)[4])(smem + 17408);
    float (*dsum)[4] = (float(*)[4])(smem + 18432);
    int* tT = (int*)(smem + 19456);

    const int t = threadIdx.x;
    const int lane = t & 63;
    const int wv = t >> 6;
    const int quad = lane >> 4;
    const int l15 = lane & 15;
    const int sample_base = blockIdx.x * MTILE;
    const int row = t >> 2, part = t & 3;  // 4 threads per sample row, 32 cols each

    // ---- phase A: load + normalize X tile into bf16 LDS; diag dot -> global atomics ----
    {
        const float4* src = (const float4*)(X + (size_t)(sample_base + row) * SZ_EMBED + part * 32);
        float4 r[8];
        float ss = 0.f;
        #pragma unroll
        for (int j = 0; j < 8; ++j) {
            r[j] = src[j];
            ss += r[j].x * r[j].x + r[j].y * r[j].y + r[j].z * r[j].z + r[j].w * r[j].w;
        }
        psum[row][part] = ss;
        if (t < MTILE) tT[t] = T[sample_base + t];
        __syncthreads();
        float inv = rsqrtf(psum[row][0] + psum[row][1] + psum[row][2] + psum[row][3] + 1e-12f);
        unsigned short* dst = xtile + row * XSTRIDE + part * 32;
        #pragma unroll
        for (int j = 0; j < 8; ++j) {
            uint2 pk;
            pk.x = (unsigned)f2bf(r[j].x * inv) | ((unsigned)f2bf(r[j].y * inv) << 16);
            pk.y = (unsigned)f2bf(r[j].z * inv) | ((unsigned)f2bf(r[j].w * inv) << 16);
            *(uint2*)(dst + j * 4) = pk;
        }
        // diag partial: dot(X[row]*inv, Pn[T[row]]) over this thread's 32 cols
        int lbl = tT[row];
        const unsigned short* prow = Pn + (size_t)lbl * SZ_EMBED + part * 32;
        float d = 0.f;
        #pragma unroll
        for (int j = 0; j < 4; ++j) {  // 4 x uint4 = 32 cols
            uint4 pv = *(const uint4*)(prow + j * 8);
            float4 xa = r[2 * j], xb = r[2 * j + 1];
            d += bfbits_lo(pv.x) * xa.x + bfbits_hi(pv.x) * xa.y;
            d += bfbits_lo(pv.y) * xa.z + bfbits_hi(pv.y) * xa.w;
            d += bfbits_lo(pv.z) * xb.x + bfbits_hi(pv.z) * xb.y;
            d += bfbits_lo(pv.w) * xb.z + bfbits_hi(pv.w) * xb.w;
        }
        dsum[row][part] = d * inv;
        __syncthreads();  // xtile + dsum ready; xtile never clobbered after this
        if (part == 0) {
            int lbl2 = tT[row];
            float dd = dsum[row][0] + dsum[row][1] + dsum[row][2] + dsum[row][3];
            float dp = __builtin_amdgcn_exp2f(fmaf(dd, -EXP_A, EXP_B));  // exp(-a(cos-mrg))
            float dn = __builtin_amdgcn_exp2f(fmaf(dd,  EXP_A, EXP_B));  // exp(+a(cos+mrg))
            atomicAdd(&pos_g[lbl2], dp);   // only contribution to pos sums
            atomicAdd(&negd_g[lbl2], dn);  // subtracted from neg sums in finalize
        }
    }

    // ---- extract A fragments into registers (resident for whole class loop) ----
    v8bf afrag[4][4];
    #pragma unroll
    for (int ri = 0; ri < 4; ++ri)
        #pragma unroll
        for (int kc = 0; kc < 4; ++kc)
            afrag[ri][kc] = *(const v8bf*)(xtile + (ri * 16 + l15) * XSTRIDE + kc * 32 + quad * 8);

    // ---- class loop: barrier-free, LDS-op-free, fully unrolled. Wave wv owns
    // col strip wv*16+l15. Double-buffered bfrag: prefetch ct+1 issued BEFORE
    // ct's MFMAs, so issue->consume spans a full iteration (~350+ cyc > L2).
    const unsigned short* bptr = Pn + (size_t)(wv * 16 + l15) * SZ_EMBED + quad * 8;
    v8bf bfrag[2][4];
    #pragma unroll
    for (int kc = 0; kc < 4; ++kc)
        bfrag[0][kc] = *(const v8bf*)(bptr + kc * 32);

    float* nrow = partial_neg + (size_t)blockIdx.x * NB_CLASSES + wv * 16 + l15;

    #pragma unroll
    for (int ct = 0; ct < NB_CLASSES / CTILE; ++ct) {
        const int cur = ct & 1;
        // prefetch next tile FIRST (independent of this iter's MFMAs)
        if (ct < NB_CLASSES / CTILE - 1) {
            const unsigned short* nb = bptr + (size_t)(ct + 1) * CTILE * SZ_EMBED;
            #pragma unroll
            for (int kc = 0; kc < 4; ++kc)
                bfrag[cur ^ 1][kc] = *(const v8bf*)(nb + kc * 32);
        }

        v4f zero = {0.f, 0.f, 0.f, 0.f};
        v4f acc[4] = {zero, zero, zero, zero};
        #pragma unroll
        for (int kc = 0; kc < 4; ++kc)
            #pragma unroll
            for (int ri = 0; ri < 4; ++ri)
                acc[ri] = __builtin_amdgcn_mfma_f32_16x16x32_bf16(afrag[ri][kc], bfrag[cur][kc], acc[ri], 0, 0, 0);

        // epilogue: exp2 per element, pairwise tree (16 rows/lane), cross-quad
        // butterfly (rows 0..63), one plain 4B store per quad-0 lane.
        float e[16];
        #pragma unroll
        for (int ri = 0; ri < 4; ++ri)
            #pragma unroll
            for (int r = 0; r < 4; ++r)
                e[ri * 4 + r] = __builtin_amdgcn_exp2f(fmaf(acc[ri][r], EXP_A, EXP_B));
        #pragma unroll
        for (int s = 8; s; s >>= 1)
            #pragma unroll
            for (int j = 0; j < s; ++j)
                e[j] += e[j + s];
        float v = e[0];
        v += __shfl_xor(v, 16);
        v += __shfl_xor(v, 32);
        if (quad == 0) nrow[ct * CTILE] = v;
    }
}

// 256 blocks, neg only. Block (g,q): sums rows [g*64, g*64+64) of class
// columns [q*256, q*256+256) into row g*64. 256 threads = 1 KB contiguous/row.
__global__ __launch_bounds__(256) void row_reduce_kernel(float* __restrict__ partial_neg) {
    const int t = threadIdx.x;
    const int g = blockIdx.x >> 2, q = blockIdx.x & 3;
    float* base = partial_neg + (size_t)g * 64 * NB_CLASSES + q * 256 + t;
    float s = 0.f;
    #pragma unroll 8
    for (int r = 0; r < 64; ++r) s += base[(size_t)r * NB_CLASSES];
    base[0] = s;
}

__global__ __launch_bounds__(256) void finalize_kernel(
    const float* __restrict__ partial_neg, const float* __restrict__ pos_g,
    const float* __restrict__ negd_g, float* __restrict__ out) {
    int t = threadIdx.x;
    // surviving neg rows: {0, 64, 128, ..., 4032}
    float4 ns = {0.f, 0.f, 0.f, 0.f};
    #pragma unroll 8
    for (int r = 0; r < 64; ++r) {
        float4 vn = *(const float4*)(partial_neg + (size_t)r * 64 * NB_CLASSES + 4 * t);
        ns.x += vn.x; ns.y += vn.y; ns.z += vn.z; ns.w += vn.w;
    }
    float4 nd = *(const float4*)(negd_g + 4 * t);
    ns.x -= nd.x; ns.y -= nd.y; ns.z -= nd.z; ns.w -= nd.w;
    float4 ps = *(const float4*)(pos_g + 4 * t);
    float lp_pos = log1pf(ps.x) + log1pf(ps.y) + log1pf(ps.z) + log1pf(ps.w);
    float lp_neg = log1pf(ns.x) + log1pf(ns.y) + log1pf(ns.z) + log1pf(ns.w);
    float valid = (ps.x != 0.f) + (ps.y != 0.f) + (ps.z != 0.f) + (ps.w != 0.f);
    #pragma unroll
    for (int off = 32; off; off >>= 1) {
        lp_pos += __shfl_xor(lp_pos, off);
        lp_neg += __shfl_xor(lp_neg, off);
        valid  += __shfl_xor(valid, off);
    }
    __shared__ float s[3][4];
    int wv = t >> 6, lane = t & 63;
    if (lane == 0) { s[0][wv] = lp_pos; s[1][wv] = lp_neg; s[2][wv] = valid; }
    __syncthreads();
    if (t == 0) {
        float P = s[0][0] + s[0][1] + s[0][2] + s[0][3];
        float Ng = s[1][0] + s[1][1] + s[1][2] + s[1][3];
        float V = s[2][0] + s[2][1] + s[2][2] + s[2][3];
        float pos_term = (V > 0.f) ? (P / fmaxf(V, 1.f)) : 0.f;
        float neg_term = Ng / (float)NB_CLASSES;
        out[0] = pos_term + neg_term;
        out[1] = pos_term;
        out[2] = neg_term;
    }
}

extern "C" void kernel_launch(void* const* d_in, const int* in_sizes, int n_in,
                              void* d_out, int out_size, void* d_ws, size_t ws_size,
                              hipStream_t stream) {
    const float* X = (const float*)d_in[0];
    const float* proxies = (const float*)d_in[1];
    const int* T = (const int*)d_in[2];
    float* out = (float*)d_out;

    // ws layout: Pn (256 KB) | pos_g (4 KB) | negd_g (4 KB) | partial_neg (16 MB)
    char* ws = (char*)d_ws;
    unsigned short* Pn = (unsigned short*)ws;
    float* pos_g = (float*)(ws + (size_t)NB_CLASSES * SZ_EMBED * sizeof(unsigned short));
    float* negd_g = pos_g + NB_CLASSES;
    float* partial_neg = negd_g + NB_CLASSES;

    hipMemsetAsync(pos_g, 0, 2 * NB_CLASSES * sizeof(float), stream);
    norm_proxies_kernel<<<NB_CLASSES / 4, 256, 0, stream>>>(proxies, Pn);
    main_kernel<<<NBLOCKS, 256, 0, stream>>>(X, T, Pn, partial_neg, pos_g, negd_g);
    row_reduce_kernel<<<256, 256, 0, stream>>>(partial_neg);
    finalize_kernel<<<1, 256, 0, stream>>>(partial_neg, pos_g, negd_g, out);
}

// Round 7
// 296.136 us; speedup vs baseline: 2.1525x; 1.1574x over previous
//
#include <hip/hip_runtime.h>
#include <math.h>

#define NB_CLASSES 1024
#define SZ_EMBED 128
#define N_SAMPLES 262144
#define MTILE 64
#define CTILE 64
#define NBLOCKS (N_SAMPLES / MTILE)  // 4096
#define XSTRIDE 136  // bf16 elems; 272B row stride -> 2-way bank alias only (free per m136)

typedef __bf16 v8bf __attribute__((ext_vector_type(8)));
typedef float v4f __attribute__((ext_vector_type(4)));

// exp(+-32*cos + 3.2) = exp2(46.166...*(+-cos) + 4.6166...)
#define EXP_A 46.16624130844683f
#define EXP_B 4.616624130844683f

// R15: LDS-staged B via global_load_lds (T3 2-phase recipe).
//  - R8-R14 mapped the register-resident-B tradeoff surface: prefetch depth
//    costs VGPRs, VGPRs cost waves, both needed to hide ~300cyc B loads.
//    Every corner lands 172-198us (or spills). Escape: stage B global->LDS
//    with ZERO VGPR cost; in-loop B read becomes ~120cyc ds_read_b128.
//  - Stage ct+1 at top of iter; MFMA+epilogue (~400cyc) covers the DMA;
//    one __syncthreads/iter publishes the buffer (vmcnt+lgkm drain).
//  - Rule #21 both-sides swizzle: linear LDS dest + inverse-swz global
//    source + swz read (col ^= (row&7)<<4) -> 2-way banks instead of 16.
//  - Tile 0 staged before phase A, drained by phase A's first barrier.
//  - LDS 52.5KB -> 3 blocks/CU (157KB<160). afrag/acc = proven R10 layout.
#define SMEM_BYTES 52480

__device__ __forceinline__ unsigned short f2bf(float f) {
    union { float f; unsigned u; } v; v.f = f;
    unsigned u = v.u;
    unsigned rounding = 0x7FFFu + ((u >> 16) & 1u);
    return (unsigned short)((u + rounding) >> 16);
}
__device__ __forceinline__ float bfbits_lo(unsigned u) {
    union { unsigned u; float f; } v; v.u = u << 16; return v.f;
}
__device__ __forceinline__ float bfbits_hi(unsigned u) {
    union { unsigned u; float f; } v; v.u = u & 0xffff0000u; return v.f;
}

__global__ __launch_bounds__(256) void norm_proxies_kernel(
    const float* __restrict__ proxies, unsigned short* __restrict__ pn) {
    int wv = threadIdx.x >> 6;
    int lane = threadIdx.x & 63;
    int row = blockIdx.x * 4 + wv;  // grid = 256 -> rows 0..1023
    const float* src = proxies + (size_t)row * SZ_EMBED + lane * 2;
    float2 x = *(const float2*)src;
    float ss = x.x * x.x + x.y * x.y;
    #pragma unroll
    for (int off = 32; off; off >>= 1) ss += __shfl_xor(ss, off);
    float inv = rsqrtf(ss + 1e-12f);
    unsigned pk = (unsigned)f2bf(x.x * inv) | ((unsigned)f2bf(x.y * inv) << 16);
    *(unsigned*)(pn + (size_t)row * SZ_EMBED + lane * 2) = pk;
}

__global__ __launch_bounds__(256) void main_kernel(
    const float* __restrict__ X, const int* __restrict__ T,
    const unsigned short* __restrict__ Pn,
    float* __restrict__ partial_neg, float* __restrict__ pos_g,
    float* __restrict__ negd_g) {
    __shared__ __align__(16) char smem[SMEM_BYTES];
    unsigned short* xtile = (unsigned short*)smem;          // 64 x 136 bf16 = 17408 B
    float (*psum)[4] = (float(*)[4])(smem + 17408);
    float (*dsum)[4] = (float(*)[4])(smem + 18432);
    int* tT = (int*)(smem + 19456);
    char* btile = smem + 19712;                             // [2][64][256B] = 32768 B

    const int t = threadIdx.x;
    const int lane = t & 63;
    const int wv = t >> 6;
    const int quad = lane >> 4;
    const int l15 = lane & 15;
    const int sample_base = blockIdx.x * MTILE;
    const int row = t >> 2, part = t & 3;  // 4 threads per sample row, 32 cols each
    const char* PnB = (const char*)Pn;

    // Stage B tile `tc` into buffer `b`. Wave wv stages its own 16 rows
    // (wv*16..+15) as 4 x global_load_lds(16B): linear LDS dest
    // (wave-uniform base + lane*16), inverse-swizzled global source so that
    // a swizzled READ (col ^ ((row&7)<<4)) returns the right data (rule #21).
#define STAGE(tc, b) do {                                                      \
        char* lb_ = btile + (b) * 16384 + wv * 4096;                           \
        _Pragma("unroll")                                                      \
        for (int c_ = 0; c_ < 4; ++c_) {                                       \
            int rw_ = c_ * 4 + (lane >> 4);                                    \
            const char* g_ = PnB + ((size_t)((tc) * 64 + wv * 16 + rw_)) * 256 \
                             + (((lane & 15) * 16) ^ ((rw_ & 7) << 4));        \
            __builtin_amdgcn_global_load_lds(                                  \
                (__attribute__((address_space(1))) const void*)g_,             \
                (__attribute__((address_space(3))) void*)(lb_ + c_ * 1024),    \
                16, 0, 0);                                                     \
        }                                                                      \
    } while (0)

    // issue tile-0 staging immediately; phase A's first barrier drains it
    STAGE(0, 0);

    // ---- phase A: load + normalize X tile into bf16 LDS; diag dot -> global atomics ----
    {
        const float4* src = (const float4*)(X + (size_t)(sample_base + row) * SZ_EMBED + part * 32);
        float4 r[8];
        float ss = 0.f;
        #pragma unroll
        for (int j = 0; j < 8; ++j) {
            r[j] = src[j];
            ss += r[j].x * r[j].x + r[j].y * r[j].y + r[j].z * r[j].z + r[j].w * r[j].w;
        }
        psum[row][part] = ss;
        if (t < MTILE) tT[t] = T[sample_base + t];
        __syncthreads();
        float inv = rsqrtf(psum[row][0] + psum[row][1] + psum[row][2] + psum[row][3] + 1e-12f);
        unsigned short* dst = xtile + row * XSTRIDE + part * 32;
        #pragma unroll
        for (int j = 0; j < 8; ++j) {
            uint2 pk;
            pk.x = (unsigned)f2bf(r[j].x * inv) | ((unsigned)f2bf(r[j].y * inv) << 16);
            pk.y = (unsigned)f2bf(r[j].z * inv) | ((unsigned)f2bf(r[j].w * inv) << 16);
            *(uint2*)(dst + j * 4) = pk;
        }
        // diag partial: dot(X[row]*inv, Pn[T[row]]) over this thread's 32 cols
        int lbl = tT[row];
        const unsigned short* prow = Pn + (size_t)lbl * SZ_EMBED + part * 32;
        float d = 0.f;
        #pragma unroll
        for (int j = 0; j < 4; ++j) {  // 4 x uint4 = 32 cols
            uint4 pv = *(const uint4*)(prow + j * 8);
            float4 xa = r[2 * j], xb = r[2 * j + 1];
            d += bfbits_lo(pv.x) * xa.x + bfbits_hi(pv.x) * xa.y;
            d += bfbits_lo(pv.y) * xa.z + bfbits_hi(pv.y) * xa.w;
            d += bfbits_lo(pv.z) * xb.x + bfbits_hi(pv.z) * xb.y;
            d += bfbits_lo(pv.w) * xb.z + bfbits_hi(pv.w) * xb.w;
        }
        dsum[row][part] = d * inv;
        __syncthreads();  // xtile + dsum ready (also drains tile-0 staging)
        if (part == 0) {
            int lbl2 = tT[row];
            float dd = dsum[row][0] + dsum[row][1] + dsum[row][2] + dsum[row][3];
            float dp = __builtin_amdgcn_exp2f(fmaf(dd, -EXP_A, EXP_B));  // exp(-a(cos-mrg))
            float dn = __builtin_amdgcn_exp2f(fmaf(dd,  EXP_A, EXP_B));  // exp(+a(cos+mrg))
            atomicAdd(&pos_g[lbl2], dp);   // only contribution to pos sums
            atomicAdd(&negd_g[lbl2], dn);  // subtracted from neg sums in finalize
        }
    }

    // ---- extract A fragments into registers (resident for whole class loop) ----
    v8bf afrag[4][4];
    #pragma unroll
    for (int ri = 0; ri < 4; ++ri)
        #pragma unroll
        for (int kc = 0; kc < 4; ++kc)
            afrag[ri][kc] = *(const v8bf*)(xtile + (ri * 16 + l15) * XSTRIDE + kc * 32 + quad * 8);

    // ---- class loop (2-phase pipeline): STAGE(ct+1) -> ds_read bfrag(cur) ->
    // MFMA -> epilogue -> __syncthreads (drains stage + publishes buffer).
    float* nrow = partial_neg + (size_t)blockIdx.x * NB_CLASSES + wv * 16 + l15;
    const int bswz = ((l15 & 7) << 4);
    const char* brow_base = btile + (wv * 16 + l15) * 256;

    #pragma unroll
    for (int ct = 0; ct < NB_CLASSES / CTILE; ++ct) {
        const int cur = ct & 1;
        if (ct < NB_CLASSES / CTILE - 1) STAGE(ct + 1, cur ^ 1);

        v8bf bfrag[4];
        #pragma unroll
        for (int kc = 0; kc < 4; ++kc)
            bfrag[kc] = *(const v8bf*)(brow_base + cur * 16384 + ((kc * 64 + quad * 16) ^ bswz));

        v4f zero = {0.f, 0.f, 0.f, 0.f};
        v4f acc[4] = {zero, zero, zero, zero};
        #pragma unroll
        for (int kc = 0; kc < 4; ++kc)
            #pragma unroll
            for (int ri = 0; ri < 4; ++ri)
                acc[ri] = __builtin_amdgcn_mfma_f32_16x16x32_bf16(afrag[ri][kc], bfrag[kc], acc[ri], 0, 0, 0);

        // epilogue: exp2 per element, pairwise tree (16 rows/lane), cross-quad
        // butterfly (rows 0..63), one plain 4B store per quad-0 lane.
        float e[16];
        #pragma unroll
        for (int ri = 0; ri < 4; ++ri)
            #pragma unroll
            for (int r = 0; r < 4; ++r)
                e[ri * 4 + r] = __builtin_amdgcn_exp2f(fmaf(acc[ri][r], EXP_A, EXP_B));
        #pragma unroll
        for (int s = 8; s; s >>= 1)
            #pragma unroll
            for (int j = 0; j < s; ++j)
                e[j] += e[j + s];
        float v = e[0];
        v += __shfl_xor(v, 16);
        v += __shfl_xor(v, 32);
        if (quad == 0) nrow[ct * CTILE] = v;

        __syncthreads();  // stage(ct+1) complete + all reads of cur done
    }
#undef STAGE
}

// 256 blocks, neg only. Block (g,q): sums rows [g*64, g*64+64) of class
// columns [q*256, q*256+256) into row g*64. 256 threads = 1 KB contiguous/row.
__global__ __launch_bounds__(256) void row_reduce_kernel(float* __restrict__ partial_neg) {
    const int t = threadIdx.x;
    const int g = blockIdx.x >> 2, q = blockIdx.x & 3;
    float* base = partial_neg + (size_t)g * 64 * NB_CLASSES + q * 256 + t;
    float s = 0.f;
    #pragma unroll 8
    for (int r = 0; r < 64; ++r) s += base[(size_t)r * NB_CLASSES];
    base[0] = s;
}

__global__ __launch_bounds__(256) void finalize_kernel(
    const float* __restrict__ partial_neg, const float* __restrict__ pos_g,
    const float* __restrict__ negd_g, float* __restrict__ out) {
    int t = threadIdx.x;
    // surviving neg rows: {0, 64, 128, ..., 4032}
    float4 ns = {0.f, 0.f, 0.f, 0.f};
    #pragma unroll 8
    for (int r = 0; r < 64; ++r) {
        float4 vn = *(const float4*)(partial_neg + (size_t)r * 64 * NB_CLASSES + 4 * t);
        ns.x += vn.x; ns.y += vn.y; ns.z += vn.z; ns.w += vn.w;
    }
    float4 nd = *(const float4*)(negd_g + 4 * t);
    ns.x -= nd.x; ns.y -= nd.y; ns.z -= nd.z; ns.w -= nd.w;
    float4 ps = *(const float4*)(pos_g + 4 * t);
    float lp_pos = log1pf(ps.x) + log1pf(ps.y) + log1pf(ps.z) + log1pf(ps.w);
    float lp_neg = log1pf(ns.x) + log1pf(ns.y) + log1pf(ns.z) + log1pf(ns.w);
    float valid = (ps.x != 0.f) + (ps.y != 0.f) + (ps.z != 0.f) + (ps.w != 0.f);
    #pragma unroll
    for (int off = 32; off; off >>= 1) {
        lp_pos += __shfl_xor(lp_pos, off);
        lp_neg += __shfl_xor(lp_neg, off);
        valid  += __shfl_xor(valid, off);
    }
    __shared__ float s[3][4];
    int wv = t >> 6, lane = t & 63;
    if (lane == 0) { s[0][wv] = lp_pos; s[1][wv] = lp_neg; s[2][wv] = valid; }
    __syncthreads();
    if (t == 0) {
        float P = s[0][0] + s[0][1] + s[0][2] + s[0][3];
        float Ng = s[1][0] + s[1][1] + s[1][2] + s[1][3];
        float V = s[2][0] + s[2][1] + s[2][2] + s[2][3];
        float pos_term = (V > 0.f) ? (P / fmaxf(V, 1.f)) : 0.f;
        float neg_term = Ng / (float)NB_CLASSES;
        out[0] = pos_term + neg_term;
        out[1] = pos_term;
        out[2] = neg_term;
    }
}

extern "C" void kernel_launch(void* const* d_in, const int* in_sizes, int n_in,
                              void* d_out, int out_size, void* d_ws, size_t ws_size,
                              hipStream_t stream) {
    const float* X = (const float*)d_in[0];
    const float* proxies = (const float*)d_in[1];
    const int* T = (const int*)d_in[2];
    float* out = (float*)d_out;

    // ws layout: Pn (256 KB) | pos_g (4 KB) | negd_g (4 KB) | partial_neg (16 MB)
    char* ws = (char*)d_ws;
    unsigned short* Pn = (unsigned short*)ws;
    float* pos_g = (float*)(ws + (size_t)NB_CLASSES * SZ_EMBED * sizeof(unsigned short));
    float* negd_g = pos_g + NB_CLASSES;
    float* partial_neg = negd_g + NB_CLASSES;

    hipMemsetAsync(pos_g, 0, 2 * NB_CLASSES * sizeof(float), stream);
    norm_proxies_kernel<<<NB_CLASSES / 4, 256, 0, stream>>>(proxies, Pn);
    main_kernel<<<NBLOCKS, 256, 0, stream>>>(X, T, Pn, partial_neg, pos_g, negd_g);
    row_reduce_kernel<<<256, 256, 0, stream>>>(partial_neg);
    finalize_kernel<<<1, 256, 0, stream>>>(partial_neg, pos_g, negd_g, out);
}

// Round 8
// 289.089 us; speedup vs baseline: 2.2050x; 1.0244x over previous
//
#include <hip/hip_runtime.h>
#include <math.h>

#define NB_CLASSES 1024
#define SZ_EMBED 128
#define N_SAMPLES 262144
#define MTILE 64
#define CTILE 64
#define NBLOCKS (N_SAMPLES / MTILE)  // 4096
#define XSTRIDE 136  // bf16 elems; 272B row stride -> 2-way bank alias only (free per m136)

typedef __bf16 v8bf __attribute__((ext_vector_type(8)));
typedef float v4f __attribute__((ext_vector_type(4)));

// exp(+-32*cos + 3.2) = exp2(46.166...*(+-cos) + 4.6166...)
#define EXP_A 46.16624130844683f
#define EXP_B 4.616624130844683f

// R16: exploit R15's win (153us, LDS-staged B, no spill).
//  - Occupancy was 30.5%: LDS 52.7KB -> 3 blocks/CU. xtile (17.4KB) is dead
//    after afrag extraction -> buffer A aliases it. Tile-0 still staged into
//    the non-aliased buffer B before phase A (keeps overlap); tile-1 stage
//    is issued after a one-time post-extraction barrier (protects alias).
//    SMEM 52.5K -> 36.1K -> 4 blocks/CU. If occupancy doesn't rise, the
//    unified-file reg footprint (~148) is the cap -> isolated for next round.
//  - memset dispatch folded into norm_proxies (blocks 0-7 zero pos_g/negd_g).
//  - Known-suboptimal, untouched: in-loop ds_read 4-way-ish bank conflict
//    (5.77M cyc, ~50cyc/iter vs 1400cyc iter wall - not the lever).
#define SMEM_BYTES 36096

__device__ __forceinline__ unsigned short f2bf(float f) {
    union { float f; unsigned u; } v; v.f = f;
    unsigned u = v.u;
    unsigned rounding = 0x7FFFu + ((u >> 16) & 1u);
    return (unsigned short)((u + rounding) >> 16);
}
__device__ __forceinline__ float bfbits_lo(unsigned u) {
    union { unsigned u; float f; } v; v.u = u << 16; return v.f;
}
__device__ __forceinline__ float bfbits_hi(unsigned u) {
    union { unsigned u; float f; } v; v.u = u & 0xffff0000u; return v.f;
}

__global__ __launch_bounds__(256) void norm_proxies_kernel(
    const float* __restrict__ proxies, unsigned short* __restrict__ pn,
    float* __restrict__ pg) {
    // blocks 0-7 also zero pos_g/negd_g (2048 contiguous floats) - replaces memset
    if (blockIdx.x < 8) pg[blockIdx.x * 256 + threadIdx.x] = 0.f;
    int wv = threadIdx.x >> 6;
    int lane = threadIdx.x & 63;
    int row = blockIdx.x * 4 + wv;  // grid = 256 -> rows 0..1023
    const float* src = proxies + (size_t)row * SZ_EMBED + lane * 2;
    float2 x = *(const float2*)src;
    float ss = x.x * x.x + x.y * x.y;
    #pragma unroll
    for (int off = 32; off; off >>= 1) ss += __shfl_xor(ss, off);
    float inv = rsqrtf(ss + 1e-12f);
    unsigned pk = (unsigned)f2bf(x.x * inv) | ((unsigned)f2bf(x.y * inv) << 16);
    *(unsigned*)(pn + (size_t)row * SZ_EMBED + lane * 2) = pk;
}

__global__ __launch_bounds__(256) void main_kernel(
    const float* __restrict__ X, const int* __restrict__ T,
    const unsigned short* __restrict__ Pn,
    float* __restrict__ partial_neg, float* __restrict__ pos_g,
    float* __restrict__ negd_g) {
    __shared__ __align__(16) char smem[SMEM_BYTES];
    // layout: [0..17408) xtile (64 x 136 bf16), ALIASED by bufA after extraction
    //         [17408..18432) psum  [18432..19456) dsum  [19456..19712) tT
    //         [19712..36096) bufB (16384 B)
    // bufA = smem + 0 (16384 B), used for odd tiles; bufB for even tiles.
    unsigned short* xtile = (unsigned short*)smem;
    float (*psum)[4] = (float(*)[4])(smem + 17408);
    float (*dsum)[4] = (float(*)[4])(smem + 18432);
    int* tT = (int*)(smem + 19456);

    const int t = threadIdx.x;
    const int lane = t & 63;
    const int wv = t >> 6;
    const int quad = lane >> 4;
    const int l15 = lane & 15;
    const int sample_base = blockIdx.x * MTILE;
    const int row = t >> 2, part = t & 3;  // 4 threads per sample row, 32 cols each
    const char* PnB = (const char*)Pn;

    // Stage B tile `tc` into buffer `b` (b=1 -> bufA@0, b=0 -> bufB@19712).
    // Wave wv stages its own 16 rows as 4 x global_load_lds(16B): linear LDS
    // dest (wave-uniform base + lane*16), inverse-swizzled global source so a
    // swizzled READ (col ^ ((row&7)<<4)) returns the right data (rule #21).
#define STAGE(tc, b) do {                                                      \
        char* lb_ = smem + ((b) ? 0 : 19712) + wv * 4096;                      \
        _Pragma("unroll")                                                      \
        for (int c_ = 0; c_ < 4; ++c_) {                                       \
            int rw_ = c_ * 4 + (lane >> 4);                                    \
            const char* g_ = PnB + ((size_t)((tc) * 64 + wv * 16 + rw_)) * 256 \
                             + (((lane & 15) * 16) ^ ((rw_ & 7) << 4));        \
            __builtin_amdgcn_global_load_lds(                                  \
                (__attribute__((address_space(1))) const void*)g_,             \
                (__attribute__((address_space(3))) void*)(lb_ + c_ * 1024),    \
                16, 0, 0);                                                     \
        }                                                                      \
    } while (0)

    // issue tile-0 staging immediately (bufB, no alias); phase A barriers drain it
    STAGE(0, 0);

    // ---- phase A: load + normalize X tile into bf16 LDS; diag dot -> global atomics ----
    {
        const float4* src = (const float4*)(X + (size_t)(sample_base + row) * SZ_EMBED + part * 32);
        float4 r[8];
        float ss = 0.f;
        #pragma unroll
        for (int j = 0; j < 8; ++j) {
            r[j] = src[j];
            ss += r[j].x * r[j].x + r[j].y * r[j].y + r[j].z * r[j].z + r[j].w * r[j].w;
        }
        psum[row][part] = ss;
        if (t < MTILE) tT[t] = T[sample_base + t];
        __syncthreads();
        float inv = rsqrtf(psum[row][0] + psum[row][1] + psum[row][2] + psum[row][3] + 1e-12f);
        unsigned short* dst = xtile + row * XSTRIDE + part * 32;
        #pragma unroll
        for (int j = 0; j < 8; ++j) {
            uint2 pk;
            pk.x = (unsigned)f2bf(r[j].x * inv) | ((unsigned)f2bf(r[j].y * inv) << 16);
            pk.y = (unsigned)f2bf(r[j].z * inv) | ((unsigned)f2bf(r[j].w * inv) << 16);
            *(uint2*)(dst + j * 4) = pk;
        }
        // diag partial: dot(X[row]*inv, Pn[T[row]]) over this thread's 32 cols
        int lbl = tT[row];
        const unsigned short* prow = Pn + (size_t)lbl * SZ_EMBED + part * 32;
        float d = 0.f;
        #pragma unroll
        for (int j = 0; j < 4; ++j) {  // 4 x uint4 = 32 cols
            uint4 pv = *(const uint4*)(prow + j * 8);
            float4 xa = r[2 * j], xb = r[2 * j + 1];
            d += bfbits_lo(pv.x) * xa.x + bfbits_hi(pv.x) * xa.y;
            d += bfbits_lo(pv.y) * xa.z + bfbits_hi(pv.y) * xa.w;
            d += bfbits_lo(pv.z) * xb.x + bfbits_hi(pv.z) * xb.y;
            d += bfbits_lo(pv.w) * xb.z + bfbits_hi(pv.w) * xb.w;
        }
        dsum[row][part] = d * inv;
        __syncthreads();  // xtile + dsum ready (also drains tile-0 staging)
        if (part == 0) {
            int lbl2 = tT[row];
            float dd = dsum[row][0] + dsum[row][1] + dsum[row][2] + dsum[row][3];
            float dp = __builtin_amdgcn_exp2f(fmaf(dd, -EXP_A, EXP_B));  // exp(-a(cos-mrg))
            float dn = __builtin_amdgcn_exp2f(fmaf(dd,  EXP_A, EXP_B));  // exp(+a(cos+mrg))
            atomicAdd(&pos_g[lbl2], dp);   // only contribution to pos sums
            atomicAdd(&negd_g[lbl2], dn);  // subtracted from neg sums in finalize
        }
    }

    // ---- extract A fragments into registers (resident for whole class loop) ----
    v8bf afrag[4][4];
    #pragma unroll
    for (int ri = 0; ri < 4; ++ri)
        #pragma unroll
        for (int kc = 0; kc < 4; ++kc)
            afrag[ri][kc] = *(const v8bf*)(xtile + (ri * 16 + l15) * XSTRIDE + kc * 32 + quad * 8);

    // all waves done reading xtile -> bufA (alias) may now be written
    __syncthreads();

    // ---- class loop (2-phase pipeline): STAGE(ct+1) -> ds_read bfrag(cur) ->
    // MFMA -> epilogue -> __syncthreads (drains stage + publishes buffer).
    float* nrow = partial_neg + (size_t)blockIdx.x * NB_CLASSES + wv * 16 + l15;
    const int bswz = ((l15 & 7) << 4);
    const int browoff = (wv * 16 + l15) * 256;

    #pragma unroll
    for (int ct = 0; ct < NB_CLASSES / CTILE; ++ct) {
        const int cur = ct & 1;
        if (ct < NB_CLASSES / CTILE - 1) STAGE(ct + 1, cur ^ 1);

        const char* bbase = smem + (cur ? 0 : 19712) + browoff;
        v8bf bfrag[4];
        #pragma unroll
        for (int kc = 0; kc < 4; ++kc)
            bfrag[kc] = *(const v8bf*)(bbase + ((kc * 64 + quad * 16) ^ bswz));

        v4f zero = {0.f, 0.f, 0.f, 0.f};
        v4f acc[4] = {zero, zero, zero, zero};
        #pragma unroll
        for (int kc = 0; kc < 4; ++kc)
            #pragma unroll
            for (int ri = 0; ri < 4; ++ri)
                acc[ri] = __builtin_amdgcn_mfma_f32_16x16x32_bf16(afrag[ri][kc], bfrag[kc], acc[ri], 0, 0, 0);

        // epilogue: exp2 per element, pairwise tree (16 rows/lane), cross-quad
        // butterfly (rows 0..63), one plain 4B store per quad-0 lane.
        float e[16];
        #pragma unroll
        for (int ri = 0; ri < 4; ++ri)
            #pragma unroll
            for (int r = 0; r < 4; ++r)
                e[ri * 4 + r] = __builtin_amdgcn_exp2f(fmaf(acc[ri][r], EXP_A, EXP_B));
        #pragma unroll
        for (int s = 8; s; s >>= 1)
            #pragma unroll
            for (int j = 0; j < s; ++j)
                e[j] += e[j + s];
        float v = e[0];
        v += __shfl_xor(v, 16);
        v += __shfl_xor(v, 32);
        if (quad == 0) nrow[ct * CTILE] = v;

        __syncthreads();  // stage(ct+1) complete + all reads of cur done
    }
#undef STAGE
}

// 256 blocks, neg only. Block (g,q): sums rows [g*64, g*64+64) of class
// columns [q*256, q*256+256) into row g*64. 256 threads = 1 KB contiguous/row.
__global__ __launch_bounds__(256) void row_reduce_kernel(float* __restrict__ partial_neg) {
    const int t = threadIdx.x;
    const int g = blockIdx.x >> 2, q = blockIdx.x & 3;
    float* base = partial_neg + (size_t)g * 64 * NB_CLASSES + q * 256 + t;
    float s = 0.f;
    #pragma unroll 8
    for (int r = 0; r < 64; ++r) s += base[(size_t)r * NB_CLASSES];
    base[0] = s;
}

__global__ __launch_bounds__(256) void finalize_kernel(
    const float* __restrict__ partial_neg, const float* __restrict__ pos_g,
    const float* __restrict__ negd_g, float* __restrict__ out) {
    int t = threadIdx.x;
    // surviving neg rows: {0, 64, 128, ..., 4032}
    float4 ns = {0.f, 0.f, 0.f, 0.f};
    #pragma unroll 8
    for (int r = 0; r < 64; ++r) {
        float4 vn = *(const float4*)(partial_neg + (size_t)r * 64 * NB_CLASSES + 4 * t);
        ns.x += vn.x; ns.y += vn.y; ns.z += vn.z; ns.w += vn.w;
    }
    float4 nd = *(const float4*)(negd_g + 4 * t);
    ns.x -= nd.x; ns.y -= nd.y; ns.z -= nd.z; ns.w -= nd.w;
    float4 ps = *(const float4*)(pos_g + 4 * t);
    float lp_pos = log1pf(ps.x) + log1pf(ps.y) + log1pf(ps.z) + log1pf(ps.w);
    float lp_neg = log1pf(ns.x) + log1pf(ns.y) + log1pf(ns.z) + log1pf(ns.w);
    float valid = (ps.x != 0.f) + (ps.y != 0.f) + (ps.z != 0.f) + (ps.w != 0.f);
    #pragma unroll
    for (int off = 32; off; off >>= 1) {
        lp_pos += __shfl_xor(lp_pos, off);
        lp_neg += __shfl_xor(lp_neg, off);
        valid  += __shfl_xor(valid, off);
    }
    __shared__ float s[3][4];
    int wv = t >> 6, lane = t & 63;
    if (lane == 0) { s[0][wv] = lp_pos; s[1][wv] = lp_neg; s[2][wv] = valid; }
    __syncthreads();
    if (t == 0) {
        float P = s[0][0] + s[0][1] + s[0][2] + s[0][3];
        float Ng = s[1][0] + s[1][1] + s[1][2] + s[1][3];
        float V = s[2][0] + s[2][1] + s[2][2] + s[2][3];
        float pos_term = (V > 0.f) ? (P / fmaxf(V, 1.f)) : 0.f;
        float neg_term = Ng / (float)NB_CLASSES;
        out[0] = pos_term + neg_term;
        out[1] = pos_term;
        out[2] = neg_term;
    }
}

extern "C" void kernel_launch(void* const* d_in, const int* in_sizes, int n_in,
                              void* d_out, int out_size, void* d_ws, size_t ws_size,
                              hipStream_t stream) {
    const float* X = (const float*)d_in[0];
    const float* proxies = (const float*)d_in[1];
    const int* T = (const int*)d_in[2];
    float* out = (float*)d_out;

    // ws layout: Pn (256 KB) | pos_g (4 KB) | negd_g (4 KB) | partial_neg (16 MB)
    char* ws = (char*)d_ws;
    unsigned short* Pn = (unsigned short*)ws;
    float* pos_g = (float*)(ws + (size_t)NB_CLASSES * SZ_EMBED * sizeof(unsigned short));
    float* negd_g = pos_g + NB_CLASSES;
    float* partial_neg = negd_g + NB_CLASSES;

    norm_proxies_kernel<<<NB_CLASSES / 4, 256, 0, stream>>>(proxies, Pn, pos_g);
    main_kernel<<<NBLOCKS, 256, 0, stream>>>(X, T, Pn, partial_neg, pos_g, negd_g);
    row_reduce_kernel<<<256, 256, 0, stream>>>(partial_neg);
    finalize_kernel<<<1, 256, 0, stream>>>(partial_neg, pos_g, negd_g, out);
}